// Round 11
// baseline (149.703 us; speedup 1.0000x reference)
//
#include <hip/hip_runtime.h>

#define HID 4096
#define MD  128
#define SB  32768          // B*S rows total
#define SLEN 4096
#define NB  8
#define NH  10
#define WIN 10
#define TLEN (SLEN - WIN + 1)   // 4087
#define NEGV -1000000000.0f
#define SLOT 49152
#define LDSZ 147456        // 3 slots

typedef _Float16 f16x8 __attribute__((ext_vector_type(8)));
typedef float f32x4 __attribute__((ext_vector_type(4)));
typedef const __attribute__((address_space(1))) f32x4* gf4p;

__device__ __forceinline__ unsigned short f2h(float f) {
  _Float16 h = (_Float16)f;
  return __builtin_bit_cast(unsigned short, h);
}

__device__ __forceinline__ f16x8 cvt8(f32x4 u, f32x4 v) {
  f16x8 r;
  r[0] = (_Float16)u[0]; r[1] = (_Float16)u[1]; r[2] = (_Float16)u[2]; r[3] = (_Float16)u[3];
  r[4] = (_Float16)v[0]; r[5] = (_Float16)v[1]; r[6] = (_Float16)v[2]; r[7] = (_Float16)v[3];
  return r;
}

__device__ __forceinline__ void gl_lds16(const void* g, void* l) {
  __builtin_amdgcn_global_load_lds(
      (const __attribute__((address_space(1))) void*)g,
      (__attribute__((address_space(3))) void*)l, 16, 0, 0);
}

// ---------------- weight preconvert: fp32 -> fp16 planes in ws ----------------
__global__ void convert_k(const float* __restrict__ W1, const float* __restrict__ W2,
                          const float* __restrict__ Wq, const float* __restrict__ Wv,
                          unsigned short* __restrict__ w1h, unsigned short* __restrict__ w2h,
                          unsigned short* __restrict__ wqvh) {
  int i = blockIdx.x * 256 + threadIdx.x;
  if (i < MD * HID) w1h[i] = f2h(W1[i]);
  if (i < MD * MD)  w2h[i] = f2h(W2[i]);
  if (i < 32 * MD) {                       // 32 padded rows: 0-9 Wq, 10-19 Wv, 20-31 zero
    unsigned short v = 0;
    if (i < NH * MD)          v = f2h(Wq[i]);
    else if (i < 2 * NH * MD) v = f2h(Wv[i - NH * MD]);
    wqvh[i] = v;
  }
}

// ---------------- fused MLP + heads: BK=128, paired A-loads (1KB/row bursts) ----------------
// grid 512 x 512 thr (8 waves), 1 block/CU. Slot (48KB): A fp16 [64][256B] @0,
// B fp16 [128][256B] @16384; ring-3. A loaded in PAIRS of K-tiles at even bodies
// (8 ops back-to-back = 1KB/row burst) into 3 register pairs pA/pB/pC; written to
// LDS one body later. Steady wait vmcnt(12)+lgkm(0)+barrier per body.
__global__ __launch_bounds__(512, 2) void fused_mlp(
    const float* __restrict__ x,
    const float* __restrict__ b1g, const float* __restrict__ b2g,
    const float* __restrict__ bvg,
    const unsigned short* __restrict__ w1h, const unsigned short* __restrict__ w2h,
    const unsigned short* __restrict__ wqvh,
    float* __restrict__ lv)
{
  extern __shared__ __align__(16) char smem[];
  char* Y = smem;   // epilogue reuse of slot0 A-region

  const int tid  = threadIdx.x;
  const int lane = tid & 63;
  const int w    = tid >> 6;           // 0..7
  const int wr   = w >> 2, wc = w & 3;
  const int l15  = lane & 15;
  const int j    = lane >> 4;
  const int m0   = blockIdx.x * 64;

  // A: thread covers row tid>>3 (0..63), 64B contiguous at byte col (tid&7)*64
  const int aRow = tid >> 3;
  const int aSw  = (aRow & 7) << 4;
  const int aC0  = ((tid & 7) * 32) ^ aSw;
  const float* xA = x + (size_t)(m0 + aRow) * HID + (tid & 7) * 16;

  f32x4 acc[2][2] = {};
  f32x4 pA0[4], pA1[4], pB0[4], pB1[4], pC0[4], pC1[4];

#define FENCE() asm volatile("" ::: "memory");

#define LOADA(AV, KT)                                                          \
  {                                                                            \
    const float* p_ = xA + (size_t)(KT) * 128;                                 \
    AV[0] = *(gf4p)(p_);                                                       \
    AV[1] = *(gf4p)(p_ + 4);                                                   \
    AV[2] = *(gf4p)(p_ + 8);                                                   \
    AV[3] = *(gf4p)(p_ + 12);                                                  \
  }

#define STAGEB(KT, SOFF)                                                       \
  {                                                                            \
    _Pragma("unroll")                                                          \
    for (int c = 0; c < 4; ++c) {                                              \
      int row = w * 16 + c * 4 + j;                                            \
      int cb  = (l15 << 4) ^ ((row & 7) << 4);                                 \
      gl_lds16(w1h + (size_t)row * HID + (KT) * 128 + (cb >> 1),               \
               smem + (SOFF) + 16384 + (w * 4 + c) * 1024);                    \
    }                                                                          \
  }

#define WRITEA(AV, SOFF)                                                       \
  {                                                                            \
    f16x8 h0_ = cvt8(AV[0], AV[1]);                                            \
    f16x8 h1_ = cvt8(AV[2], AV[3]);                                            \
    char* d_ = smem + (SOFF) + aRow * 256;                                     \
    *(f16x8*)(d_ + aC0) = h0_;                                                 \
    *(f16x8*)(d_ + (aC0 ^ 16)) = h1_;                                          \
  }

#define DOMFMA(SOFF)                                                           \
  {                                                                            \
    const char* Ab = smem + (SOFF);                                            \
    const char* Bb = Ab + 16384;                                               \
    _Pragma("unroll")                                                          \
    for (int ks = 0; ks < 4; ++ks) {                                           \
      f16x8 af[2], bf[2];                                                      \
      _Pragma("unroll")                                                        \
      for (int mf = 0; mf < 2; ++mf) {                                         \
        int rr = wr * 32 + mf * 16 + l15;                                      \
        af[mf] = *(const f16x8*)(Ab + rr * 256 +                               \
                                 ((ks * 64 + j * 16) ^ ((rr & 7) << 4)));      \
      }                                                                        \
      _Pragma("unroll")                                                        \
      for (int nf = 0; nf < 2; ++nf) {                                         \
        int n = wc * 32 + nf * 16 + l15;                                       \
        bf[nf] = *(const f16x8*)(Bb + n * 256 +                                \
                                 ((ks * 64 + j * 16) ^ ((n & 7) << 4)));       \
      }                                                                        \
      _Pragma("unroll")                                                        \
      for (int mf = 0; mf < 2; ++mf)                                           \
        _Pragma("unroll")                                                      \
        for (int nf = 0; nf < 2; ++nf)                                         \
          acc[mf][nf] = __builtin_amdgcn_mfma_f32_16x16x32_f16(af[mf], bf[nf], \
                                                          acc[mf][nf], 0, 0, 0); \
    }                                                                          \
  }

#define WAITBAR(N)                                                             \
  asm volatile("s_waitcnt vmcnt(" #N ") lgkmcnt(0)" ::: "memory");             \
  __builtin_amdgcn_s_barrier();                                                \
  asm volatile("" ::: "memory");

#define WRNEXT(AV)                                                             \
  { int sN_ = sR + SLOT; if (sN_ == LDSZ) sN_ = 0; WRITEA(AV, sN_); }

#define ADV() sR += SLOT; if (sR == LDSZ) sR = 0; sW += SLOT; if (sW == LDSZ) sW = 0;

// even body t: stage B(t+2); load A-pair (t+4,t+5); write A(t+1); compute t
#define BODYE(T, PL0, PL1, PW)                                                 \
  WAITBAR(12);                                                                 \
  STAGEB((T) + 2, sW);                                                         \
  FENCE();                                                                     \
  LOADA(PL0, (T) + 4);                                                         \
  LOADA(PL1, (T) + 5);                                                         \
  WRNEXT(PW);                                                                  \
  DOMFMA(sR);                                                                  \
  ADV();

// odd body t: stage B(t+2); write A(t+1); compute t
#define BODYO(T, PW)                                                           \
  WAITBAR(12);                                                                 \
  STAGEB((T) + 2, sW);                                                         \
  WRNEXT(PW);                                                                  \
  DOMFMA(sR);                                                                  \
  ADV();

  // prologue: A(0),A(1), B(0), A(2),A(3), B(1)  -> 24 ops
  LOADA(pA0, 0); FENCE();
  LOADA(pA1, 1); FENCE();
  STAGEB(0, 0); FENCE();
  LOADA(pB0, 2); FENCE();
  LOADA(pB1, 3); FENCE();
  STAGEB(1, SLOT);
  asm volatile("s_waitcnt vmcnt(16)" ::: "memory");   // A(0),A(1) landed
  WRITEA(pA0, 0);

  int sR = 0, sW = 2 * SLOT;
  // steady 6-body cycles: bodies 0..23
  #pragma unroll 1
  for (int tb = 0; tb < 24; tb += 6) {
    BODYE(tb + 0, pC0, pC1, pA1);
    BODYO(tb + 1, pB0);
    BODYE(tb + 2, pA0, pA1, pB1);
    BODYO(tb + 3, pC0);
    BODYE(tb + 4, pB0, pB1, pC1);
    BODYO(tb + 5, pA0);
  }
  // peeled bodies 24..27 (standard)
  BODYE(24, pC0, pC1, pA1);
  BODYO(25, pB0);
  BODYE(26, pA0, pA1, pB1);     // loads A(30),A(31)
  BODYO(27, pC0);
  // body 28: stage B(30); write A(29); compute 28
  WAITBAR(12);
  STAGEB(30, sW);
  WRNEXT(pC1);
  DOMFMA(sR);
  ADV();
  // body 29: stage B(31); write A(30); compute 29 (drains A30,A31,B29 -> keep B30)
  WAITBAR(4);
  STAGEB(31, sW);
  WRNEXT(pA0);
  DOMFMA(sR);
  ADV();
  // body 30: write A(31); compute 30 (drain B30, keep B31)
  WAITBAR(4);
  WRNEXT(pA1);
  DOMFMA(sR);
  sR += SLOT; if (sR == LDSZ) sR = 0;
  // body 31: drain; compute 31
  WAITBAR(0);
  DOMFMA(sR);

  // ---- y1 = relu(acc + b1) -> Y fp16 [64][256B] XOR-swizzled ----
  #pragma unroll
  for (int mf = 0; mf < 2; ++mf)
    #pragma unroll
    for (int nf = 0; nf < 2; ++nf) {
      const int col = wc * 32 + nf * 16 + l15;
      const float bb = b1g[col];
      #pragma unroll
      for (int r = 0; r < 4; ++r) {
        float t = acc[mf][nf][r] + bb; t = t > 0.f ? t : 0.f;
        int row = wr * 32 + mf * 16 + j * 4 + r;
        *(unsigned short*)(Y + row * 256 + ((col * 2) ^ ((row & 7) << 4))) = f2h(t);
      }
    }
  __syncthreads();

  // ---- layer 2: y2 = relu(y1 @ W2^T + b2), K=128 ----
  const int g  = w >> 1, ch = w & 1;
  const int erow = g * 16 + l15;
  const int esw  = (erow & 7) << 4;
  f16x8 a2[4];
  {
    const char* base = Y + erow * 256;
    #pragma unroll
    for (int ks = 0; ks < 4; ++ks)
      a2[ks] = *(const f16x8*)(base + ((ks * 64 + j * 16) ^ esw));
  }
  f32x4 acc2[4] = {};
  const unsigned short* w2b = w2h + (size_t)(ch * 64 + l15) * MD + j * 8;
  #pragma unroll
  for (int ks = 0; ks < 4; ++ks)
    #pragma unroll
    for (int nf = 0; nf < 4; ++nf) {
      f16x8 bf = *(const f16x8*)(w2b + (size_t)(nf * 16) * MD + ks * 32);
      acc2[nf] = __builtin_amdgcn_mfma_f32_16x16x32_f16(a2[ks], bf, acc2[nf], 0, 0, 0);
    }
  __syncthreads();   // all Y reads done before overwrite
  #pragma unroll
  for (int nf = 0; nf < 4; ++nf) {
    const int col = ch * 64 + nf * 16 + l15;
    const float bb = b2g[col];
    #pragma unroll
    for (int r = 0; r < 4; ++r) {
      int row = g * 16 + j * 4 + r;
      float t = acc2[nf][r] + bb; t = t > 0.f ? t : 0.f;
      *(unsigned short*)(Y + row * 256 + ((col * 2) ^ ((row & 7) << 4))) = f2h(t);
    }
  }
  __syncthreads();

  // ---- layer 3: heads (N=32 padded, 20 valid) ----
  f16x8 a3[4];
  {
    const char* base = Y + erow * 256;
    #pragma unroll
    for (int ks = 0; ks < 4; ++ks)
      a3[ks] = *(const f16x8*)(base + ((ks * 64 + j * 16) ^ esw));
  }
  f32x4 acc3 = {};
  const int col3 = ch * 16 + l15;
  const unsigned short* wqb = wqvh + (size_t)col3 * MD + j * 8;
  #pragma unroll
  for (int ks = 0; ks < 4; ++ks) {
    f16x8 bf = *(const f16x8*)(wqb + ks * 32);
    acc3 = __builtin_amdgcn_mfma_f32_16x16x32_f16(a3[ks], bf, acc3, 0, 0, 0);
  }
  if (col3 < 2 * NH) {
    const float badd = (col3 < NH) ? 0.f : bvg[col3 - NH];
    const size_t plane = (size_t)col3 * SB;
    #pragma unroll
    for (int r = 0; r < 4; ++r) {
      int s = m0 + g * 16 + j * 4 + r;
      lv[plane + s] = acc3[r] + badd;
    }
  }
}

// ---------------- sliding-window softmax + per-chunk max ----------------
__global__ void windows_k(const float* __restrict__ lv, const int* __restrict__ mask,
                          float* __restrict__ partial) {
  const int chunk = blockIdx.x, b = blockIdx.y, h = blockIdx.z;
  const int t0 = chunk * 256;
  const int tid = threadIdx.x;
  __shared__ float lsh[272], vsh[272];
  const float* lp = lv + (size_t)h * SB + b * SLEN;
  const float* vp = lv + (size_t)(NH + h) * SB + b * SLEN;
  const int* mp = mask + b * SLEN;
  for (int i = tid; i < 256 + WIN - 1; i += 256) {
    int t = t0 + i;
    if (t < SLEN) {
      float l = lp[t];
      if (mp[t] == 0) l = NEGV;
      lsh[i] = l; vsh[i] = vp[t];
    }
  }
  __syncthreads();
  float wmax = -INFINITY;
  int t = t0 + tid;
  if (t < TLEN) {
    float m = lsh[tid];
    #pragma unroll
    for (int jj = 1; jj < WIN; ++jj) m = fmaxf(m, lsh[tid + jj]);
    float den = 0.f, num = 0.f;
    #pragma unroll
    for (int jj = 0; jj < WIN; ++jj) {
      float e = __expf(lsh[tid + jj] - m);
      den += e; num += e * vsh[tid + jj];
    }
    wmax = num / den;
  }
  #pragma unroll
  for (int o = 32; o > 0; o >>= 1) wmax = fmaxf(wmax, __shfl_down(wmax, o, 64));
  __shared__ float red[4];
  if ((tid & 63) == 0) red[tid >> 6] = wmax;
  __syncthreads();
  if (tid == 0) {
    float r = fmaxf(fmaxf(red[0], red[1]), fmaxf(red[2], red[3]));
    partial[(b * NH + h) * 16 + chunk] = r;
  }
}

// ---------------- final: max over chunks, sum heads, + bias ----------------
__global__ void finalize_k(const float* __restrict__ partial, const float* __restrict__ bias,
                           float* __restrict__ out) {
  const int tid = threadIdx.x;  // 1 block, 128 thr
  __shared__ float hm[80];
  if (tid < NB * NH) {
    float m = -INFINITY;
    #pragma unroll
    for (int c = 0; c < 16; ++c) m = fmaxf(m, partial[tid * 16 + c]);
    hm[tid] = m;
  }
  __syncthreads();
  if (tid < NB) {
    float s = bias[0];
    #pragma unroll
    for (int h = 0; h < NH; ++h) s += hm[tid * NH + h];
    out[tid] = s;
  }
}

extern "C" void kernel_launch(void* const* d_in, const int* in_sizes, int n_in,
                              void* d_out, int out_size, void* d_ws, size_t ws_size,
                              hipStream_t stream) {
  const float* x    = (const float*)d_in[0];
  const int*   mask = (const int*)d_in[1];
  const float* W1   = (const float*)d_in[2];
  const float* b1   = (const float*)d_in[3];
  const float* W2   = (const float*)d_in[4];
  const float* b2   = (const float*)d_in[5];
  const float* Wq   = (const float*)d_in[6];
  const float* Wv   = (const float*)d_in[7];
  const float* bv   = (const float*)d_in[8];
  const float* bias = (const float*)d_in[9];

  char* ws = (char*)d_ws;
  unsigned short* w1h  = (unsigned short*)ws;                   // 1,048,576 B
  unsigned short* w2h  = (unsigned short*)(ws + 1048576);       //    32,768 B
  unsigned short* wqvh = (unsigned short*)(ws + 1081344);       //     8,192 B
  float* lv            = (float*)(ws + 1089536);                // 20*32768*4 = 2,621,440 B
  float* partial       = (float*)(ws + 3710976);                //     5,120 B
  float* out = (float*)d_out;

  hipLaunchKernelGGL(convert_k, dim3(2048), dim3(256), 0, stream, W1, W2, Wq, Wv, w1h, w2h, wqvh);
  hipLaunchKernelGGL(fused_mlp, dim3(SB / 64), dim3(512), LDSZ, stream,
                     x, b1, b2, bv, w1h, w2h, wqvh, lv);
  hipLaunchKernelGGL(windows_k, dim3(16, NB, NH), dim3(256), 0, stream, lv, mask, partial);
  hipLaunchKernelGGL(finalize_k, dim3(1), dim3(128), 0, stream, partial, bias, out);
}

// Round 12
// 135.857 us; speedup vs baseline: 1.1019x; 1.1019x over previous
//
#include <hip/hip_runtime.h>

#define HID 4096
#define MD  128
#define SB  32768          // B*S rows total
#define SLEN 4096
#define NB  8
#define NH  10
#define WIN 10
#define TLEN (SLEN - WIN + 1)   // 4087
#define NEGV -1000000000.0f
#define SLOT 49152
#define LDSZ 147456        // 3 slots

typedef _Float16 f16x8 __attribute__((ext_vector_type(8)));
typedef float f32x4 __attribute__((ext_vector_type(4)));
typedef const __attribute__((address_space(1))) f32x4* gf4p;

__device__ __forceinline__ unsigned short f2h(float f) {
  _Float16 h = (_Float16)f;
  return __builtin_bit_cast(unsigned short, h);
}

__device__ __forceinline__ f16x8 cvt8(f32x4 u, f32x4 v) {
  f16x8 r;
  r[0] = (_Float16)u[0]; r[1] = (_Float16)u[1]; r[2] = (_Float16)u[2]; r[3] = (_Float16)u[3];
  r[4] = (_Float16)v[0]; r[5] = (_Float16)v[1]; r[6] = (_Float16)v[2]; r[7] = (_Float16)v[3];
  return r;
}

__device__ __forceinline__ void gl_lds16(const void* g, void* l) {
  __builtin_amdgcn_global_load_lds(
      (const __attribute__((address_space(1))) void*)g,
      (__attribute__((address_space(3))) void*)l, 16, 0, 0);
}

// ---------------- weight preconvert: fp32 -> fp16 planes in ws ----------------
__global__ void convert_k(const float* __restrict__ W1, const float* __restrict__ W2,
                          const float* __restrict__ Wq, const float* __restrict__ Wv,
                          unsigned short* __restrict__ w1h, unsigned short* __restrict__ w2h,
                          unsigned short* __restrict__ wqvh) {
  int i = blockIdx.x * 256 + threadIdx.x;
  if (i < MD * HID) w1h[i] = f2h(W1[i]);
  if (i < MD * MD)  w2h[i] = f2h(W2[i]);
  if (i < 32 * MD) {                       // 32 padded rows: 0-9 Wq, 10-19 Wv, 20-31 zero
    unsigned short v = 0;
    if (i < NH * MD)          v = f2h(Wq[i]);
    else if (i < 2 * NH * MD) v = f2h(Wv[i - NH * MD]);
    wqvh[i] = v;
  }
}

// ---------------- fused MLP + heads: BK=128, depth-3 A-prefetch in regs ----------------
// grid 512 x 512 thr (8 waves), 1 block/CU. Slot (48KB): A fp16 [64][256B] @0,
// B fp16 [128][256B] @16384; ring-3. At step t: issue A(t+3)->regs + B(t+2)->LDS,
// ds_write A(t+1), compute tile t. Steady in-flight: 16 VMEM ops/thread (8KB/wave
// of HBM A-reads). One vmcnt(8)+lgkmcnt(0)+barrier per step; queue never drains.
__global__ __launch_bounds__(512, 2) void fused_mlp(
    const float* __restrict__ x,
    const float* __restrict__ b1g, const float* __restrict__ b2g,
    const float* __restrict__ bvg,
    const unsigned short* __restrict__ w1h, const unsigned short* __restrict__ w2h,
    const unsigned short* __restrict__ wqvh,
    float* __restrict__ lv)
{
  extern __shared__ __align__(16) char smem[];
  char* Y = smem;   // epilogue reuse of slot0 A-region (tile31 lives in slot1)

  const int tid  = threadIdx.x;
  const int lane = tid & 63;
  const int w    = tid >> 6;           // 0..7
  const int wr   = w >> 2, wc = w & 3;
  const int l15  = lane & 15;
  const int j    = lane >> 4;
  const int m0   = blockIdx.x * 64;

  // A: thread covers row tid>>3 (0..63), 64B contiguous at byte col (tid&7)*64
  const int aRow = tid >> 3;
  const int aSw  = (aRow & 7) << 4;
  const int aC0  = ((tid & 7) * 32) ^ aSw;
  const float* xA = x + (size_t)(m0 + aRow) * HID + (tid & 7) * 16;

  f32x4 acc[2][2] = {};
  f32x4 av0[4], av1[4], av2[4];

#define LOADA(AV, KT)                                                          \
  {                                                                            \
    const float* p_ = xA + (size_t)(KT) * 128;                                 \
    AV[0] = *(gf4p)(p_);                                                       \
    AV[1] = *(gf4p)(p_ + 4);                                                   \
    AV[2] = *(gf4p)(p_ + 8);                                                   \
    AV[3] = *(gf4p)(p_ + 12);                                                  \
  }

#define STAGEB(KT, SOFF)                                                       \
  {                                                                            \
    _Pragma("unroll")                                                          \
    for (int c = 0; c < 4; ++c) {                                              \
      int row = w * 16 + c * 4 + j;                                            \
      int cb  = (l15 << 4) ^ ((row & 7) << 4);                                 \
      gl_lds16(w1h + (size_t)row * HID + (KT) * 128 + (cb >> 1),               \
               smem + (SOFF) + 16384 + (w * 4 + c) * 1024);                    \
    }                                                                          \
  }

#define WRITEA(AV, SOFF)                                                       \
  {                                                                            \
    f16x8 h0_ = cvt8(AV[0], AV[1]);                                            \
    f16x8 h1_ = cvt8(AV[2], AV[3]);                                            \
    char* d_ = smem + (SOFF) + aRow * 256;                                     \
    *(f16x8*)(d_ + aC0) = h0_;                                                 \
    *(f16x8*)(d_ + (aC0 ^ 16)) = h1_;                                          \
  }

#define DOMFMA(SOFF)                                                           \
  {                                                                            \
    const char* Ab = smem + (SOFF);                                            \
    const char* Bb = Ab + 16384;                                               \
    _Pragma("unroll")                                                          \
    for (int ks = 0; ks < 4; ++ks) {                                           \
      f16x8 af[2], bf[2];                                                      \
      _Pragma("unroll")                                                        \
      for (int mf = 0; mf < 2; ++mf) {                                         \
        int rr = wr * 32 + mf * 16 + l15;                                      \
        af[mf] = *(const f16x8*)(Ab + rr * 256 +                               \
                                 ((ks * 64 + j * 16) ^ ((rr & 7) << 4)));      \
      }                                                                        \
      _Pragma("unroll")                                                        \
      for (int nf = 0; nf < 2; ++nf) {                                         \
        int n = wc * 32 + nf * 16 + l15;                                       \
        bf[nf] = *(const f16x8*)(Bb + n * 256 +                                \
                                 ((ks * 64 + j * 16) ^ ((n & 7) << 4)));       \
      }                                                                        \
      _Pragma("unroll")                                                        \
      for (int mf = 0; mf < 2; ++mf)                                           \
        _Pragma("unroll")                                                      \
        for (int nf = 0; nf < 2; ++nf)                                         \
          acc[mf][nf] = __builtin_amdgcn_mfma_f32_16x16x32_f16(af[mf], bf[nf], \
                                                          acc[mf][nf], 0, 0, 0); \
    }                                                                          \
  }

#define WAITBAR()                                                              \
  asm volatile("s_waitcnt vmcnt(8) lgkmcnt(0)" ::: "memory");                  \
  __builtin_amdgcn_s_barrier();                                                \
  asm volatile("" ::: "memory");

#define BODY(T, AVL, AVW)                                                      \
  WAITBAR();                                                                   \
  LOADA(AVL, (T) + 3);                                                         \
  STAGEB((T) + 2, sW);                                                         \
  { int sN_ = sR + SLOT; if (sN_ == LDSZ) sN_ = 0; WRITEA(AVW, sN_); }         \
  DOMFMA(sR);                                                                  \
  sR += SLOT; if (sR == LDSZ) sR = 0;                                          \
  sW += SLOT; if (sW == LDSZ) sW = 0;

  // prologue: A0,B0,A1,B1,A2 issued (20 ops); A0 landed after vmcnt(16)
  LOADA(av0, 0); STAGEB(0, 0);
  LOADA(av1, 1); STAGEB(1, SLOT);
  LOADA(av2, 2);
  asm volatile("s_waitcnt vmcnt(16)" ::: "memory");
  WRITEA(av0, 0);

  int sR = 0, sW = 2 * SLOT;
  // steady: t = 0..26 (all guards true: A up to 29, B up to 28)
  #pragma unroll 1
  for (int tb = 0; tb < 27; tb += 3) {
    BODY(tb + 0, av0, av1);
    BODY(tb + 1, av1, av2);
    BODY(tb + 2, av2, av0);
  }
  // t=27: A30, B29
  WAITBAR(); LOADA(av0, 30); STAGEB(29, sW);
  { int sN_ = sR + SLOT; if (sN_ == LDSZ) sN_ = 0; WRITEA(av1, sN_); }
  DOMFMA(sR);
  sR += SLOT; if (sR == LDSZ) sR = 0; sW += SLOT; if (sW == LDSZ) sW = 0;
  // t=28: A31, B30
  WAITBAR(); LOADA(av1, 31); STAGEB(30, sW);
  { int sN_ = sR + SLOT; if (sN_ == LDSZ) sN_ = 0; WRITEA(av2, sN_); }
  DOMFMA(sR);
  sR += SLOT; if (sR == LDSZ) sR = 0; sW += SLOT; if (sW == LDSZ) sW = 0;
  // t=29: B31
  WAITBAR(); STAGEB(31, sW);
  { int sN_ = sR + SLOT; if (sN_ == LDSZ) sN_ = 0; WRITEA(av0, sN_); }
  DOMFMA(sR);
  sR += SLOT; if (sR == LDSZ) sR = 0;
  // t=30: drain all VMEM (A31 + B31)
  asm volatile("s_waitcnt vmcnt(0) lgkmcnt(0)" ::: "memory");
  __builtin_amdgcn_s_barrier();
  asm volatile("" ::: "memory");
  { int sN_ = sR + SLOT; if (sN_ == LDSZ) sN_ = 0; WRITEA(av1, sN_); }
  DOMFMA(sR);
  sR += SLOT; if (sR == LDSZ) sR = 0;
  // t=31 (slot1; Y=slot0 A-region is disjoint)
  asm volatile("s_waitcnt lgkmcnt(0)" ::: "memory");
  __builtin_amdgcn_s_barrier();
  asm volatile("" ::: "memory");
  DOMFMA(sR);

  // ---- y1 = relu(acc + b1) -> Y fp16 [64][256B] XOR-swizzled ----
  #pragma unroll
  for (int mf = 0; mf < 2; ++mf)
    #pragma unroll
    for (int nf = 0; nf < 2; ++nf) {
      const int col = wc * 32 + nf * 16 + l15;
      const float bb = b1g[col];
      #pragma unroll
      for (int r = 0; r < 4; ++r) {
        float t = acc[mf][nf][r] + bb; t = t > 0.f ? t : 0.f;
        int row = wr * 32 + mf * 16 + j * 4 + r;
        *(unsigned short*)(Y + row * 256 + ((col * 2) ^ ((row & 7) << 4))) = f2h(t);
      }
    }
  __syncthreads();

  // ---- layer 2: y2 = relu(y1 @ W2^T + b2), K=128 ----
  const int g  = w >> 1, ch = w & 1;
  const int erow = g * 16 + l15;
  const int esw  = (erow & 7) << 4;
  f16x8 a2[4];
  {
    const char* base = Y + erow * 256;
    #pragma unroll
    for (int ks = 0; ks < 4; ++ks)
      a2[ks] = *(const f16x8*)(base + ((ks * 64 + j * 16) ^ esw));
  }
  f32x4 acc2[4] = {};
  const unsigned short* w2b = w2h + (size_t)(ch * 64 + l15) * MD + j * 8;
  #pragma unroll
  for (int ks = 0; ks < 4; ++ks)
    #pragma unroll
    for (int nf = 0; nf < 4; ++nf) {
      f16x8 bf = *(const f16x8*)(w2b + (size_t)(nf * 16) * MD + ks * 32);
      acc2[nf] = __builtin_amdgcn_mfma_f32_16x16x32_f16(a2[ks], bf, acc2[nf], 0, 0, 0);
    }
  __syncthreads();   // all Y reads done before overwrite
  #pragma unroll
  for (int nf = 0; nf < 4; ++nf) {
    const int col = ch * 64 + nf * 16 + l15;
    const float bb = b2g[col];
    #pragma unroll
    for (int r = 0; r < 4; ++r) {
      int row = g * 16 + j * 4 + r;
      float t = acc2[nf][r] + bb; t = t > 0.f ? t : 0.f;
      *(unsigned short*)(Y + row * 256 + ((col * 2) ^ ((row & 7) << 4))) = f2h(t);
    }
  }
  __syncthreads();

  // ---- layer 3: heads (N=32 padded, 20 valid) ----
  f16x8 a3[4];
  {
    const char* base = Y + erow * 256;
    #pragma unroll
    for (int ks = 0; ks < 4; ++ks)
      a3[ks] = *(const f16x8*)(base + ((ks * 64 + j * 16) ^ esw));
  }
  f32x4 acc3 = {};
  const int col3 = ch * 16 + l15;
  const unsigned short* wqb = wqvh + (size_t)col3 * MD + j * 8;
  #pragma unroll
  for (int ks = 0; ks < 4; ++ks) {
    f16x8 bf = *(const f16x8*)(wqb + ks * 32);
    acc3 = __builtin_amdgcn_mfma_f32_16x16x32_f16(a3[ks], bf, acc3, 0, 0, 0);
  }
  if (col3 < 2 * NH) {
    const float badd = (col3 < NH) ? 0.f : bvg[col3 - NH];
    const size_t plane = (size_t)col3 * SB;
    #pragma unroll
    for (int r = 0; r < 4; ++r) {
      int s = m0 + g * 16 + j * 4 + r;
      lv[plane + s] = acc3[r] + badd;
    }
  }
}

// ---------------- sliding-window softmax + per-chunk max ----------------
__global__ void windows_k(const float* __restrict__ lv, const int* __restrict__ mask,
                          float* __restrict__ partial) {
  const int chunk = blockIdx.x, b = blockIdx.y, h = blockIdx.z;
  const int t0 = chunk * 256;
  const int tid = threadIdx.x;
  __shared__ float lsh[272], vsh[272];
  const float* lp = lv + (size_t)h * SB + b * SLEN;
  const float* vp = lv + (size_t)(NH + h) * SB + b * SLEN;
  const int* mp = mask + b * SLEN;
  for (int i = tid; i < 256 + WIN - 1; i += 256) {
    int t = t0 + i;
    if (t < SLEN) {
      float l = lp[t];
      if (mp[t] == 0) l = NEGV;
      lsh[i] = l; vsh[i] = vp[t];
    }
  }
  __syncthreads();
  float wmax = -INFINITY;
  int t = t0 + tid;
  if (t < TLEN) {
    float m = lsh[tid];
    #pragma unroll
    for (int jj = 1; jj < WIN; ++jj) m = fmaxf(m, lsh[tid + jj]);
    float den = 0.f, num = 0.f;
    #pragma unroll
    for (int jj = 0; jj < WIN; ++jj) {
      float e = __expf(lsh[tid + jj] - m);
      den += e; num += e * vsh[tid + jj];
    }
    wmax = num / den;
  }
  #pragma unroll
  for (int o = 32; o > 0; o >>= 1) wmax = fmaxf(wmax, __shfl_down(wmax, o, 64));
  __shared__ float red[4];
  if ((tid & 63) == 0) red[tid >> 6] = wmax;
  __syncthreads();
  if (tid == 0) {
    float r = fmaxf(fmaxf(red[0], red[1]), fmaxf(red[2], red[3]));
    partial[(b * NH + h) * 16 + chunk] = r;
  }
}

// ---------------- final: max over chunks, sum heads, + bias ----------------
__global__ void finalize_k(const float* __restrict__ partial, const float* __restrict__ bias,
                           float* __restrict__ out) {
  const int tid = threadIdx.x;  // 1 block, 128 thr
  __shared__ float hm[80];
  if (tid < NB * NH) {
    float m = -INFINITY;
    #pragma unroll
    for (int c = 0; c < 16; ++c) m = fmaxf(m, partial[tid * 16 + c]);
    hm[tid] = m;
  }
  __syncthreads();
  if (tid < NB) {
    float s = bias[0];
    #pragma unroll
    for (int h = 0; h < NH; ++h) s += hm[tid * NH + h];
    out[tid] = s;
  }
}

extern "C" void kernel_launch(void* const* d_in, const int* in_sizes, int n_in,
                              void* d_out, int out_size, void* d_ws, size_t ws_size,
                              hipStream_t stream) {
  const float* x    = (const float*)d_in[0];
  const int*   mask = (const int*)d_in[1];
  const float* W1   = (const float*)d_in[2];
  const float* b1   = (const float*)d_in[3];
  const float* W2   = (const float*)d_in[4];
  const float* b2   = (const float*)d_in[5];
  const float* Wq   = (const float*)d_in[6];
  const float* Wv   = (const float*)d_in[7];
  const float* bv   = (const float*)d_in[8];
  const float* bias = (const float*)d_in[9];

  char* ws = (char*)d_ws;
  unsigned short* w1h  = (unsigned short*)ws;                   // 1,048,576 B
  unsigned short* w2h  = (unsigned short*)(ws + 1048576);       //    32,768 B
  unsigned short* wqvh = (unsigned short*)(ws + 1081344);       //     8,192 B
  float* lv            = (float*)(ws + 1089536);                // 20*32768*4 = 2,621,440 B
  float* partial       = (float*)(ws + 3710976);                //     5,120 B
  float* out = (float*)d_out;

  hipLaunchKernelGGL(convert_k, dim3(2048), dim3(256), 0, stream, W1, W2, Wq, Wv, w1h, w2h, wqvh);
  hipLaunchKernelGGL(fused_mlp, dim3(SB / 64), dim3(512), LDSZ, stream,
                     x, b1, b2, bv, w1h, w2h, wqvh, lv);
  hipLaunchKernelGGL(windows_k, dim3(16, NB, NH), dim3(256), 0, stream, lv, mask, partial);
  hipLaunchKernelGGL(finalize_k, dim3(1), dim3(128), 0, stream, partial, bias, out);
}